// Round 4
// baseline (612.729 us; speedup 1.0000x reference)
//
#include <hip/hip_runtime.h>
#include <math.h>

constexpr int CW = 3125;   // valid width
constexpr int CC = 256;    // channels
constexpr int CB = 4;      // batch
constexpr int NHh = 8;     // heads
constexpr int KDd = 64;    // qk head dim
constexpr int HDd = 32;    // v head dim

typedef __attribute__((ext_vector_type(8))) short short8;
typedef __attribute__((ext_vector_type(4))) float f32x4;
typedef __attribute__((ext_vector_type(4))) unsigned int uint4v;

__device__ inline unsigned short f2bf(float x) {
  unsigned int u = __float_as_uint(x);
  unsigned int r = u + 0x7FFFu + ((u >> 16) & 1u);
  return (unsigned short)(r >> 16);
}

__device__ inline void gload_lds16(const void* g, void* l) {
  typedef __attribute__((address_space(3))) unsigned int lds_u32;
  typedef const __attribute__((address_space(1))) unsigned int glob_u32;
  __builtin_amdgcn_global_load_lds((glob_u32*)g, (lds_u32*)l, 16, 0, 0);
}

// x (b,256,CW) channel-major  ->  xcur (b,CW,256) position-major
__global__ __launch_bounds__(256) void transpose_x(const float* __restrict__ src,
                                                   float* __restrict__ dst) {
  __shared__ float sT[64][65];
  int l0 = blockIdx.x * 64, c0 = blockIdx.y * 64, bI = blockIdx.z;
  int tid = threadIdx.x;
  for (int i = tid; i < 4096; i += 256) {
    int ll = i & 63, cc = i >> 6;
    int l = l0 + ll;
    sT[cc][ll] = (l < CW) ? src[((size_t)bI * CC + c0 + cc) * CW + l] : 0.f;
  }
  __syncthreads();
  for (int i = tid; i < 4096; i += 256) {
    int cc = i & 63, ll = i >> 6;
    int l = l0 + ll;
    if (l < CW) dst[((size_t)bI * CW + l) * CC + c0 + cc] = sT[cc][ll];
  }
}

// Weight staging image: [otile][ktile=16][kchunk=4][o=128][16B]; ktiles 8-15 = lo copy
__global__ __launch_bounds__(256) void prep_w(const float* __restrict__ W0, int O0,
                                              const float* __restrict__ W1,
                                              unsigned short* __restrict__ img,
                                              int Ototal) {
  int t = blockIdx.x * 256 + threadIdx.x;
  if (t >= Ototal * 32) return;
  int o = t >> 5, ch = t & 31;
  const float* row = (o < O0) ? (W0 + (size_t)o * CC) : (W1 + (size_t)(o - O0) * CC);
  unsigned short h[8];
#pragma unroll
  for (int j = 0; j < 8; j++) h[j] = f2bf(row[ch * 8 + j]);
  uint4v v;
  v[0] = (unsigned)h[0] | ((unsigned)h[1] << 16);
  v[1] = (unsigned)h[2] | ((unsigned)h[3] << 16);
  v[2] = (unsigned)h[4] | ((unsigned)h[5] << 16);
  v[3] = (unsigned)h[6] | ((unsigned)h[7] << 16);
  int otile = o >> 7, oo = o & 127;
  int ktile = ch >> 2, kchunk = ch & 3;
  uint4v* img4 = (uint4v*)img;
  size_t idx = ((size_t)otile * 16 + ktile) * 512 + kchunk * 128 + oo;
  img4[idx] = v;
  img4[idx + 8 * 512] = v;
}

// x staging from xcur rows (dense p' = bI*CW+l), split hi/lo bf16.
__global__ __launch_bounds__(256) void prep_x(const float* __restrict__ X,
                                              unsigned short* __restrict__ img, int P) {
  int ptile = blockIdx.x, cq = blockIdx.y;
  int c0 = cq * 64;
  __shared__ float sX[64][129];
  int tid = threadIdx.x;
  for (int i = tid; i < 64 * 128; i += 256) {
    int cc = i & 63, pp = i >> 6;
    int p = ptile * 128 + pp;
    sX[cc][pp] = (p < P) ? X[(size_t)p * CC + c0 + cc] : 0.f;
  }
  __syncthreads();
  uint4v* img4 = (uint4v*)img;
  for (int i = tid; i < 1024; i += 256) {
    int ch = i >> 7, pp = i & 127;
    float f[8];
    unsigned short h[8], lo[8];
#pragma unroll
    for (int j = 0; j < 8; j++) f[j] = sX[ch * 8 + j][pp];
#pragma unroll
    for (int j = 0; j < 8; j++) {
      h[j] = f2bf(f[j]);
      float hif = __uint_as_float((unsigned)h[j] << 16);
      lo[j] = f2bf(f[j] - hif);
    }
    uint4v vh, vl;
    vh[0] = (unsigned)h[0] | ((unsigned)h[1] << 16);
    vh[1] = (unsigned)h[2] | ((unsigned)h[3] << 16);
    vh[2] = (unsigned)h[4] | ((unsigned)h[5] << 16);
    vh[3] = (unsigned)h[6] | ((unsigned)h[7] << 16);
    vl[0] = (unsigned)lo[0] | ((unsigned)lo[1] << 16);
    vl[1] = (unsigned)lo[2] | ((unsigned)lo[3] << 16);
    vl[2] = (unsigned)lo[4] | ((unsigned)lo[5] << 16);
    vl[3] = (unsigned)lo[6] | ((unsigned)lo[7] << 16);
    int ktile = cq * 2 + (ch >> 2), kchunk = ch & 3;
    size_t idx = ((size_t)ptile * 16 + ktile) * 512 + kchunk * 128 + pp;
    img4[idx] = vh;
    img4[idx + 8 * 512] = vl;
  }
}

// MFMA GEMM over dense valid positions p' = bI*CW + l.
// MODE 0: fused qkv (O=1280) -> q/k (b,NH,L,64), v0pm (b,L,256)
// MODE 2: proj (O=256) -> out (b,256,CW)
template <int MODE>
__global__ __launch_bounds__(256) void gemm_bn(
    const unsigned short* __restrict__ Aimg, const unsigned short* __restrict__ Ximg,
    const float* __restrict__ G0, const float* __restrict__ B0,
    const float* __restrict__ M0, const float* __restrict__ V0,
    const float* __restrict__ G1, const float* __restrict__ B1,
    const float* __restrict__ M1, const float* __restrict__ V1,
    float* __restrict__ q, float* __restrict__ k, float* __restrict__ v0pm,
    float* __restrict__ out, int L, int P) {
  __shared__ __align__(16) unsigned short sA[4096];
  __shared__ __align__(16) unsigned short sB[4096];
  int tid = threadIdx.x;
  int wid = tid >> 6, lane = tid & 63;
  int wr = wid >> 1, wc = wid & 1;
  int otile = blockIdx.y, ptile = blockIdx.x;
  f32x4 acc[4][4] = {};
  size_t aBase = ((size_t)otile * 16) * 4096;
  size_t bBase = ((size_t)ptile * 16) * 4096;
  int r = lane & 15, kb = lane >> 4;
  for (int kt = 0; kt < 16; kt++) {
    __syncthreads();
#pragma unroll
    for (int i = 0; i < 4; i++) {
      int c = wid * 4 + i;
      if (c < 8) {
        gload_lds16(Aimg + aBase + kt * 4096 + c * 512 + lane * 8, sA + c * 512 + lane * 8);
      } else {
        gload_lds16(Ximg + bBase + kt * 4096 + (c - 8) * 512 + lane * 8,
                    sB + (c - 8) * 512 + lane * 8);
      }
    }
    __syncthreads();
    short8 a[4], b[4];
#pragma unroll
    for (int mi = 0; mi < 4; mi++)
      a[mi] = *(const short8*)&sA[kb * 1024 + (wr * 64 + mi * 16 + r) * 8];
#pragma unroll
    for (int ni = 0; ni < 4; ni++)
      b[ni] = *(const short8*)&sB[kb * 1024 + (wc * 64 + ni * 16 + r) * 8];
    if (MODE == 0) {
#pragma unroll
      for (int mi = 0; mi < 4; mi++)
#pragma unroll
        for (int ni = 0; ni < 4; ni++)
          acc[ni][mi] = __builtin_amdgcn_mfma_f32_16x16x32_bf16(b[ni], a[mi], acc[ni][mi], 0, 0, 0);
    } else {
#pragma unroll
      for (int mi = 0; mi < 4; mi++)
#pragma unroll
        for (int ni = 0; ni < 4; ni++)
          acc[mi][ni] = __builtin_amdgcn_mfma_f32_16x16x32_bf16(a[mi], b[ni], acc[mi][ni], 0, 0, 0);
    }
  }
  int cl = lane & 15, r4 = lane >> 4;
  if (MODE == 0) {
#pragma unroll
    for (int mi = 0; mi < 4; mi++) {
      int o = otile * 128 + wr * 64 + mi * 16 + cl;
      float s, sh;
      if (o >= 1024) {
        int oc = o - 1024;
        s = G1[oc] * rsqrtf(V1[oc] + 1e-5f);
        sh = B1[oc] - M1[oc] * s;
      } else {
        s = G0[o] * rsqrtf(V0[o] + 1e-5f);
        sh = B0[o] - M0[o] * s;
      }
      int nh = (o & 1023) >> 7, sp = (o >> 6) & 1, d = o & 63;
      int oc = o - 1024;
#pragma unroll
      for (int ni = 0; ni < 4; ni++) {
#pragma unroll
        for (int reg = 0; reg < 4; reg++) {
          int p = ptile * 128 + wc * 64 + ni * 16 + r4 * 4 + reg;
          if (p >= P) continue;
          int bI = p / CW, l = p - bI * CW;
          float y = acc[ni][mi][reg] * s + sh;
          if (o < 1024) {
            float* dst = sp ? k : q;
            dst[(((size_t)(bI * NHh + nh)) * L + l) * KDd + d] = y;
          } else {
            v0pm[((size_t)bI * L + l) * CC + oc] = y;
          }
        }
      }
    }
  } else {
#pragma unroll
    for (int mi = 0; mi < 4; mi++) {
#pragma unroll
      for (int reg = 0; reg < 4; reg++) {
        int o = otile * 128 + wr * 64 + mi * 16 + r4 * 4 + reg;
        float s = G0[o] * rsqrtf(V0[o] + 1e-5f);
        float sh = B0[o] - M0[o] * s;
#pragma unroll
        for (int ni = 0; ni < 4; ni++) {
          int p = ptile * 128 + wc * 64 + ni * 16 + cl;
          if (p >= P) continue;
          int bI = p / CW, l = p - bI * CW;
          out[((size_t)bI * CC + o) * CW + l] = acc[mi][ni][reg] * s + sh;
        }
      }
    }
  }
}

// Fill pad rows l in [CW, L): conv1x1(0)+BN = per-channel constant.
__global__ __launch_bounds__(256) void pad_fill(
    const float* __restrict__ G0, const float* __restrict__ B0,
    const float* __restrict__ M0, const float* __restrict__ V0,
    const float* __restrict__ G1, const float* __restrict__ B1,
    const float* __restrict__ M1, const float* __restrict__ V1,
    float* __restrict__ q, float* __restrict__ k, float* __restrict__ v0pm, int L) {
  int pidx = blockIdx.x;
  int nPad = L - CW;
  int bI = pidx / nPad, l = CW + (pidx - bI * nPad);
  int tid = threadIdx.x;
  for (int o = tid; o < 1280; o += 256) {
    if (o < 1024) {
      float s = G0[o] * rsqrtf(V0[o] + 1e-5f);
      float sh = B0[o] - M0[o] * s;
      int nh = o >> 7, sp = (o >> 6) & 1, d = o & 63;
      float* dst = sp ? k : q;
      dst[(((size_t)(bI * NHh + nh)) * L + l) * KDd + d] = sh;
    } else {
      int oc = o - 1024;
      float s = G1[oc] * rsqrtf(V1[oc] + 1e-5f);
      float sh = B1[oc] - M1[oc] * s;
      v0pm[((size_t)bI * L + l) * CC + oc] = sh;
    }
  }
}

// Fused pair of attention levels. One wave per B*B-position block.
// Block: pos = base0 + idx*s2, idx = a*B + b; level A = digit a (stride B*s2),
// level B = digit b (stride s2). Lane = qk dim d; v dim = lane&31.
template <int B>
__global__ __launch_bounds__(256) void attn_pair(
    const float* __restrict__ q, const float* __restrict__ k,
    const float* __restrict__ vin, float* __restrict__ vout,
    int L, int s2, int bpb) {
  constexpr int B2 = B * B;
  int lane = threadIdx.x & 63;
  int gid = blockIdx.x * 4 + (threadIdx.x >> 6);
  int bh = gid / bpb;
  int g = gid - bh * bpb;
  int bI = bh >> 3, nh = bh & 7;
  int hi = g / s2, lo = g - hi * s2;
  int base0 = hi * B2 * s2 + lo;
  size_t qkBase = ((size_t)bh * L + base0) * KDd + lane;
  float qv[B2], kv[B2], vv[B2];
#pragma unroll
  for (int idx = 0; idx < B2; idx++) {
    size_t o = (size_t)(idx * s2) * KDd;
    qv[idx] = q[qkBase + o];
    kv[idx] = k[qkBase + o];
  }
  int dd = lane & 31, half = lane >> 5;
  size_t vBase = ((size_t)bI * L + base0) * CC + nh * HDd + dd;
#pragma unroll
  for (int idx = 0; idx < B2; idx++)
    vv[idx] = vin[vBase + (size_t)(idx * s2) * CC];

  // Level A: attention over digit a, groups fixed b
#pragma unroll
  for (int b = 0; b < B; b++) {
    float sc[B2];
#pragma unroll
    for (int J = 0; J < B; J++)
#pragma unroll
      for (int j = 0; j < B; j++) sc[J * B + j] = kv[J * B + b] * qv[j * B + b];
#pragma unroll
    for (int off = 1; off < 64; off <<= 1)
#pragma unroll
      for (int t = 0; t < B2; t++) sc[t] += __shfl_xor(sc[t], off, 64);
    float tmp[B];
#pragma unroll
    for (int J = 0; J < B; J++) {
      float mx = sc[J * B + 0];
#pragma unroll
      for (int j = 1; j < B; j++) mx = fmaxf(mx, sc[J * B + j]);
      float sum = 0.f, acc = 0.f;
#pragma unroll
      for (int j = 0; j < B; j++) {
        float e = __expf((sc[J * B + j] - mx) * 0.125f);
        sum += e;
        acc += e * vv[j * B + b];
      }
      tmp[J] = acc / sum;
    }
#pragma unroll
    for (int J = 0; J < B; J++) vv[J * B + b] = tmp[J];
  }
  // Level B: attention over digit b, groups fixed a
#pragma unroll
  for (int a = 0; a < B; a++) {
    float sc[B2];
#pragma unroll
    for (int J = 0; J < B; J++)
#pragma unroll
      for (int j = 0; j < B; j++) sc[J * B + j] = kv[a * B + J] * qv[a * B + j];
#pragma unroll
    for (int off = 1; off < 64; off <<= 1)
#pragma unroll
      for (int t = 0; t < B2; t++) sc[t] += __shfl_xor(sc[t], off, 64);
    float tmp[B];
#pragma unroll
    for (int J = 0; J < B; J++) {
      float mx = sc[J * B + 0];
#pragma unroll
      for (int j = 1; j < B; j++) mx = fmaxf(mx, sc[J * B + j]);
      float sum = 0.f, acc = 0.f;
#pragma unroll
      for (int j = 0; j < B; j++) {
        float e = __expf((sc[J * B + j] - mx) * 0.125f);
        sum += e;
        acc += e * vv[a * B + j];
      }
      tmp[J] = acc / sum;
    }
#pragma unroll
    for (int J = 0; J < B; J++) vv[a * B + J] = tmp[J];
  }
#pragma unroll
  for (int idx = 0; idx < B2; idx++)
    if ((idx & 1) == half) vout[vBase + (size_t)(idx * s2) * CC] = vv[idx];
}

// Single level (base-5 last level, stride 1)
template <int BASE>
__global__ __launch_bounds__(256) void attn_level(
    const float* __restrict__ q, const float* __restrict__ k,
    const float* __restrict__ vin, float* __restrict__ vout,
    int L, int stride, int gpb) {
  int lane = threadIdx.x & 63;
  int gid = blockIdx.x * 4 + (threadIdx.x >> 6);
  int bh = gid / gpb;
  int g = gid - bh * gpb;
  int bI = bh >> 3, nh = bh & 7;
  int i0 = g / stride;
  int k2 = g - i0 * stride;
  int posBase = i0 * BASE * stride + k2;
  size_t qkBase = ((size_t)bh * L + posBase) * KDd + lane;
  float qv[BASE], kv[BASE];
#pragma unroll
  for (int j = 0; j < BASE; j++) {
    qv[j] = q[qkBase + (size_t)(j * stride) * KDd];
    kv[j] = k[qkBase + (size_t)(j * stride) * KDd];
  }
  float sc[BASE * BASE];
#pragma unroll
  for (int J = 0; J < BASE; J++)
#pragma unroll
    for (int j = 0; j < BASE; j++) sc[J * BASE + j] = kv[J] * qv[j];
#pragma unroll
  for (int off = 1; off < 64; off <<= 1)
#pragma unroll
    for (int t = 0; t < BASE * BASE; t++) sc[t] += __shfl_xor(sc[t], off, 64);
  int dd = lane & 31, half = lane >> 5;
  size_t vBase = ((size_t)bI * L + posBase) * CC + nh * HDd + dd;
  float vv[BASE];
#pragma unroll
  for (int j = 0; j < BASE; j++) vv[j] = vin[vBase + (size_t)(j * stride) * CC];
#pragma unroll
  for (int J = 0; J < BASE; J++) {
    if ((J & 1) == half) {
      float mx = sc[J * BASE + 0];
#pragma unroll
      for (int j = 1; j < BASE; j++) mx = fmaxf(mx, sc[J * BASE + j]);
      float sum = 0.f, acc = 0.f;
#pragma unroll
      for (int j = 0; j < BASE; j++) {
        float e = __expf((sc[J * BASE + j] - mx) * 0.125f);
        sum += e;
        acc += e * vv[j];
      }
      vout[vBase + (size_t)(J * stride) * CC] = acc / sum;
    }
  }
}

// xcur(b,CW,256) += v2 + BN(dwconv3(v0pm))
__global__ __launch_bounds__(256) void combine(
    float* __restrict__ xcur, const float* __restrict__ v0pm,
    const float* __restrict__ vfin, const float* __restrict__ peW,
    const float* __restrict__ G, const float* __restrict__ Bb,
    const float* __restrict__ M, const float* __restrict__ V, int L) {
  int idx = blockIdx.x * 256 + threadIdx.x;
  if (idx >= CB * CC * CW) return;
  int ch = idx & 255;
  int t = idx >> 8;
  int l = t % CW;
  int bI = t / CW;
  size_t row = ((size_t)bI * L + l) * CC + ch;
  float left = (l > 0) ? v0pm[row - CC] : 0.f;
  float mid = v0pm[row];
  float right = (l + 1 < L) ? v0pm[row + CC] : 0.f;
  float conv = left * peW[ch * 3 + 0] + mid * peW[ch * 3 + 1] + right * peW[ch * 3 + 2];
  float s = G[ch] * rsqrtf(V[ch] + 1e-5f);
  float pe = conv * s + (Bb[ch] - M[ch] * s);
  xcur[((size_t)bI * CW + l) * CC + ch] += vfin[row] + pe;
}

extern "C" void kernel_launch(void* const* d_in, const int* in_sizes, int n_in,
                              void* d_out, int out_size, void* d_ws, size_t ws_size,
                              hipStream_t stream) {
  const float* x = (const float*)d_in[0];
  const float* qk_W = (const float*)d_in[1];
  const float* qk_g = (const float*)d_in[2];
  const float* qk_b = (const float*)d_in[3];
  const float* qk_m = (const float*)d_in[4];
  const float* qk_v = (const float*)d_in[5];
  const float* v_W = (const float*)d_in[6];
  const float* v_g = (const float*)d_in[7];
  const float* v_b = (const float*)d_in[8];
  const float* v_m = (const float*)d_in[9];
  const float* v_v = (const float*)d_in[10];
  const float* pe_W = (const float*)d_in[11];
  const float* pe_g = (const float*)d_in[12];
  const float* pe_b = (const float*)d_in[13];
  const float* pe_m = (const float*)d_in[14];
  const float* pe_v = (const float*)d_in[15];
  const float* proj_W = (const float*)d_in[16];
  const float* proj_g = (const float*)d_in[17];
  const float* proj_b = (const float*)d_in[18];
  const float* proj_m = (const float*)d_in[19];
  const float* proj_v = (const float*)d_in[20];

  char* ws = (char*)d_ws;
  size_t off = 0;
  auto alloc = [&](size_t bytes) {
    char* p = ws + off;
    off += (bytes + 255) & ~(size_t)255;
    return (float*)p;
  };
  const int Lmax = 4096;
  float* xcur = alloc((size_t)CB * CW * CC * 4);
  float* qbuf = alloc((size_t)CB * NHh * Lmax * KDd * 4);
  float* kbuf = alloc((size_t)CB * NHh * Lmax * KDd * 4);
  float* v0pm = alloc((size_t)CB * Lmax * CC * 4);
  float* vA = alloc((size_t)CB * Lmax * CC * 4);  // aliases Ximg during GEMM
  float* vB = alloc((size_t)CB * Lmax * CC * 4);
  unsigned short* Wimg = (unsigned short*)alloc((size_t)10 * 16 * 8192);
  unsigned short* Ximg = (unsigned short*)vA;
  (void)ws_size;

  {
    dim3 gt((CW + 63) / 64, 4, CB);
    transpose_x<<<gt, 256, 0, stream>>>(x, xcur);
  }

  const int P = CB * CW;          // dense valid positions
  const int ptiles = (P + 127) / 128;
  const int bases[2] = {5, 4};
  const int Ls[2] = {3125, 4096};
  int nElems = CB * CC * CW;
  for (int blk = 0; blk < 2; blk++) {
    int L = Ls[blk];
    prep_w<<<(1280 * 32 + 255) / 256, 256, 0, stream>>>(
        qk_W + (size_t)blk * 1024 * CC, 1024, v_W + (size_t)blk * CC * CC, Wimg, 1280);
    dim3 gx(ptiles, 4);
    prep_x<<<gx, 256, 0, stream>>>(xcur, Ximg, P);
    dim3 gg(ptiles, 10);
    gemm_bn<0><<<gg, 256, 0, stream>>>(
        Wimg, Ximg, qk_g + blk * 1024, qk_b + blk * 1024, qk_m + blk * 1024,
        qk_v + blk * 1024, v_g + blk * CC, v_b + blk * CC, v_m + blk * CC,
        v_v + blk * CC, qbuf, kbuf, v0pm, nullptr, L, P);
    if (L > CW) {
      pad_fill<<<CB * (L - CW), 256, 0, stream>>>(
          qk_g + blk * 1024, qk_b + blk * 1024, qk_m + blk * 1024, qk_v + blk * 1024,
          v_g + blk * CC, v_b + blk * CC, v_m + blk * CC, v_v + blk * CC,
          qbuf, kbuf, v0pm, L);
    }

    const float* vin = v0pm;
    if (bases[blk] == 5) {
      // levels (0,1): s2=125; (2,3): s2=5; level 4 single: stride 1
      int bpb = 3125 / 25;
      attn_pair<5><<<(CB * NHh * bpb) / 4, 256, 0, stream>>>(qbuf, kbuf, vin, vA, L, 125, bpb);
      attn_pair<5><<<(CB * NHh * bpb) / 4, 256, 0, stream>>>(qbuf, kbuf, vA, vB, L, 5, bpb);
      int gpb = 3125 / 5;
      attn_level<5><<<(CB * NHh * gpb) / 4, 256, 0, stream>>>(qbuf, kbuf, vB, vA, L, 1, gpb);
    } else {
      int bpb = 4096 / 16;
      attn_pair<4><<<(CB * NHh * bpb) / 4, 256, 0, stream>>>(qbuf, kbuf, vin, vA, L, 256, bpb);
      attn_pair<4><<<(CB * NHh * bpb) / 4, 256, 0, stream>>>(qbuf, kbuf, vA, vB, L, 16, bpb);
      attn_pair<4><<<(CB * NHh * bpb) / 4, 256, 0, stream>>>(qbuf, kbuf, vB, vA, L, 1, bpb);
    }
    combine<<<(nElems + 255) / 256, 256, 0, stream>>>(
        xcur, v0pm, vA, pe_W + (size_t)blk * CC * 3, pe_g + blk * CC,
        pe_b + blk * CC, pe_m + blk * CC, pe_v + blk * CC, L);
  }
  {
    prep_w<<<(256 * 32 + 255) / 256, 256, 0, stream>>>(proj_W, 256, nullptr, Wimg, 256);
    dim3 gx(ptiles, 4);
    prep_x<<<gx, 256, 0, stream>>>(xcur, Ximg, P);
    dim3 gg(ptiles, 2);
    gemm_bn<2><<<gg, 256, 0, stream>>>(
        Wimg, Ximg, proj_g, proj_b, proj_m, proj_v, nullptr, nullptr, nullptr,
        nullptr, nullptr, nullptr, nullptr, (float*)d_out, CW, P);
  }
}

// Round 5
// 373.342 us; speedup vs baseline: 1.6412x; 1.6412x over previous
//
#include <hip/hip_runtime.h>
#include <math.h>

constexpr int CW = 3125;   // valid width
constexpr int CC = 256;    // channels
constexpr int CB = 4;      // batch
constexpr int NHh = 8;     // heads
constexpr int KDd = 64;    // qk head dim
constexpr int HDd = 32;    // v head dim

typedef __attribute__((ext_vector_type(8))) short short8;
typedef __attribute__((ext_vector_type(4))) float f32x4;
typedef __attribute__((ext_vector_type(4))) unsigned int uint4v;

__device__ inline unsigned short f2bf(float x) {
  unsigned int u = __float_as_uint(x);
  unsigned int r = u + 0x7FFFu + ((u >> 16) & 1u);
  return (unsigned short)(r >> 16);
}

__device__ inline void gload_lds16(const void* g, void* l) {
  typedef __attribute__((address_space(3))) unsigned int lds_u32;
  typedef const __attribute__((address_space(1))) unsigned int glob_u32;
  __builtin_amdgcn_global_load_lds((glob_u32*)g, (lds_u32*)l, 16, 0, 0);
}

// x (b,256,CW) channel-major  ->  xcur (b,CW,256) position-major
__global__ __launch_bounds__(256) void transpose_x(const float* __restrict__ src,
                                                   float* __restrict__ dst) {
  __shared__ float sT[64][65];
  int l0 = blockIdx.x * 64, c0 = blockIdx.y * 64, bI = blockIdx.z;
  int tid = threadIdx.x;
  for (int i = tid; i < 4096; i += 256) {
    int ll = i & 63, cc = i >> 6;
    int l = l0 + ll;
    sT[cc][ll] = (l < CW) ? src[((size_t)bI * CC + c0 + cc) * CW + l] : 0.f;
  }
  __syncthreads();
  for (int i = tid; i < 4096; i += 256) {
    int cc = i & 63, ll = i >> 6;
    int l = l0 + ll;
    if (l < CW) dst[((size_t)bI * CW + l) * CC + c0 + cc] = sT[cc][ll];
  }
}

// Weight staging image: [otile][ktile=16][kchunk=4][o=128][16B]; ktiles 8-15 = lo copy
__global__ __launch_bounds__(256) void prep_w(const float* __restrict__ W0, int O0,
                                              const float* __restrict__ W1,
                                              unsigned short* __restrict__ img,
                                              int Ototal) {
  int t = blockIdx.x * 256 + threadIdx.x;
  if (t >= Ototal * 32) return;
  int o = t >> 5, ch = t & 31;
  const float* row = (o < O0) ? (W0 + (size_t)o * CC) : (W1 + (size_t)(o - O0) * CC);
  unsigned short h[8];
#pragma unroll
  for (int j = 0; j < 8; j++) h[j] = f2bf(row[ch * 8 + j]);
  uint4v v;
  v[0] = (unsigned)h[0] | ((unsigned)h[1] << 16);
  v[1] = (unsigned)h[2] | ((unsigned)h[3] << 16);
  v[2] = (unsigned)h[4] | ((unsigned)h[5] << 16);
  v[3] = (unsigned)h[6] | ((unsigned)h[7] << 16);
  int otile = o >> 7, oo = o & 127;
  int ktile = ch >> 2, kchunk = ch & 3;
  uint4v* img4 = (uint4v*)img;
  size_t idx = ((size_t)otile * 16 + ktile) * 512 + kchunk * 128 + oo;
  img4[idx] = v;
  img4[idx + 8 * 512] = v;
}

// x staging from xcur rows (dense p' = bI*CW+l), split hi/lo bf16.
__global__ __launch_bounds__(256) void prep_x(const float* __restrict__ X,
                                              unsigned short* __restrict__ img, int P) {
  int ptile = blockIdx.x, cq = blockIdx.y;
  int c0 = cq * 64;
  __shared__ float sX[64][129];
  int tid = threadIdx.x;
  for (int i = tid; i < 64 * 128; i += 256) {
    int cc = i & 63, pp = i >> 6;
    int p = ptile * 128 + pp;
    sX[cc][pp] = (p < P) ? X[(size_t)p * CC + c0 + cc] : 0.f;
  }
  __syncthreads();
  uint4v* img4 = (uint4v*)img;
  for (int i = tid; i < 1024; i += 256) {
    int ch = i >> 7, pp = i & 127;
    float f[8];
    unsigned short h[8], lo[8];
#pragma unroll
    for (int j = 0; j < 8; j++) f[j] = sX[ch * 8 + j][pp];
#pragma unroll
    for (int j = 0; j < 8; j++) {
      h[j] = f2bf(f[j]);
      float hif = __uint_as_float((unsigned)h[j] << 16);
      lo[j] = f2bf(f[j] - hif);
    }
    uint4v vh, vl;
    vh[0] = (unsigned)h[0] | ((unsigned)h[1] << 16);
    vh[1] = (unsigned)h[2] | ((unsigned)h[3] << 16);
    vh[2] = (unsigned)h[4] | ((unsigned)h[5] << 16);
    vh[3] = (unsigned)h[6] | ((unsigned)h[7] << 16);
    vl[0] = (unsigned)lo[0] | ((unsigned)lo[1] << 16);
    vl[1] = (unsigned)lo[2] | ((unsigned)lo[3] << 16);
    vl[2] = (unsigned)lo[4] | ((unsigned)lo[5] << 16);
    vl[3] = (unsigned)lo[6] | ((unsigned)lo[7] << 16);
    int ktile = cq * 2 + (ch >> 2), kchunk = ch & 3;
    size_t idx = ((size_t)ptile * 16 + ktile) * 512 + kchunk * 128 + pp;
    img4[idx] = vh;
    img4[idx + 8 * 512] = vl;
  }
}

// MFMA GEMM over dense valid positions p' = bI*CW + l.
// MODE 0: fused qkv (O=1280) -> q/k bf16 hi/lo images [bh][L][64hi|64lo], v0pm (b,L,256) fp32
// MODE 2: proj (O=256) -> out (b,256,CW)
template <int MODE>
__global__ __launch_bounds__(256) void gemm_bn(
    const unsigned short* __restrict__ Aimg, const unsigned short* __restrict__ Ximg,
    const float* __restrict__ G0, const float* __restrict__ B0,
    const float* __restrict__ M0, const float* __restrict__ V0,
    const float* __restrict__ G1, const float* __restrict__ B1,
    const float* __restrict__ M1, const float* __restrict__ V1,
    unsigned short* __restrict__ qimg, unsigned short* __restrict__ kimg,
    float* __restrict__ v0pm, float* __restrict__ out, int L, int P) {
  __shared__ __align__(16) unsigned short sA[4096];
  __shared__ __align__(16) unsigned short sB[4096];
  int tid = threadIdx.x;
  int wid = tid >> 6, lane = tid & 63;
  int wr = wid >> 1, wc = wid & 1;
  int otile = blockIdx.y, ptile = blockIdx.x;
  f32x4 acc[4][4] = {};
  size_t aBase = ((size_t)otile * 16) * 4096;
  size_t bBase = ((size_t)ptile * 16) * 4096;
  int r = lane & 15, kb = lane >> 4;
  for (int kt = 0; kt < 16; kt++) {
    __syncthreads();
#pragma unroll
    for (int i = 0; i < 4; i++) {
      int c = wid * 4 + i;
      if (c < 8) {
        gload_lds16(Aimg + aBase + kt * 4096 + c * 512 + lane * 8, sA + c * 512 + lane * 8);
      } else {
        gload_lds16(Ximg + bBase + kt * 4096 + (c - 8) * 512 + lane * 8,
                    sB + (c - 8) * 512 + lane * 8);
      }
    }
    __syncthreads();
    short8 a[4], b[4];
#pragma unroll
    for (int mi = 0; mi < 4; mi++)
      a[mi] = *(const short8*)&sA[kb * 1024 + (wr * 64 + mi * 16 + r) * 8];
#pragma unroll
    for (int ni = 0; ni < 4; ni++)
      b[ni] = *(const short8*)&sB[kb * 1024 + (wc * 64 + ni * 16 + r) * 8];
    if (MODE == 0) {
#pragma unroll
      for (int mi = 0; mi < 4; mi++)
#pragma unroll
        for (int ni = 0; ni < 4; ni++)
          acc[ni][mi] = __builtin_amdgcn_mfma_f32_16x16x32_bf16(b[ni], a[mi], acc[ni][mi], 0, 0, 0);
    } else {
#pragma unroll
      for (int mi = 0; mi < 4; mi++)
#pragma unroll
        for (int ni = 0; ni < 4; ni++)
          acc[mi][ni] = __builtin_amdgcn_mfma_f32_16x16x32_bf16(a[mi], b[ni], acc[mi][ni], 0, 0, 0);
    }
  }
  int cl = lane & 15, r4 = lane >> 4;
  if (MODE == 0) {
#pragma unroll
    for (int mi = 0; mi < 4; mi++) {
      int o = otile * 128 + wr * 64 + mi * 16 + cl;
      float s, sh;
      if (o >= 1024) {
        int oc = o - 1024;
        s = G1[oc] * rsqrtf(V1[oc] + 1e-5f);
        sh = B1[oc] - M1[oc] * s;
      } else {
        s = G0[o] * rsqrtf(V0[o] + 1e-5f);
        sh = B0[o] - M0[o] * s;
      }
      int nh = (o & 1023) >> 7, sp = (o >> 6) & 1, d = o & 63;
      int oc = o - 1024;
#pragma unroll
      for (int ni = 0; ni < 4; ni++) {
#pragma unroll
        for (int reg = 0; reg < 4; reg++) {
          int p = ptile * 128 + wc * 64 + ni * 16 + r4 * 4 + reg;
          if (p >= P) continue;
          int bI = p / CW, l = p - bI * CW;
          float y = acc[ni][mi][reg] * s + sh;
          if (o < 1024) {
            unsigned short* dst = sp ? kimg : qimg;
            size_t rowoff = (((size_t)(bI * NHh + nh)) * L + l) * 128 + d;
            unsigned short hi = f2bf(y);
            float hif = __uint_as_float((unsigned)hi << 16);
            dst[rowoff] = hi;
            dst[rowoff + 64] = f2bf(y - hif);
          } else {
            v0pm[((size_t)bI * L + l) * CC + oc] = y;
          }
        }
      }
    }
  } else {
#pragma unroll
    for (int mi = 0; mi < 4; mi++) {
#pragma unroll
      for (int reg = 0; reg < 4; reg++) {
        int o = otile * 128 + wr * 64 + mi * 16 + r4 * 4 + reg;
        float s = G0[o] * rsqrtf(V0[o] + 1e-5f);
        float sh = B0[o] - M0[o] * s;
#pragma unroll
        for (int ni = 0; ni < 4; ni++) {
          int p = ptile * 128 + wc * 64 + ni * 16 + cl;
          if (p >= P) continue;
          int bI = p / CW, l = p - bI * CW;
          out[((size_t)bI * CC + o) * CW + l] = acc[mi][ni][reg] * s + sh;
        }
      }
    }
  }
}

// Fill pad rows l in [CW, L): conv1x1(0)+BN = per-channel constant.
__global__ __launch_bounds__(256) void pad_fill(
    const float* __restrict__ G0, const float* __restrict__ B0,
    const float* __restrict__ M0, const float* __restrict__ V0,
    const float* __restrict__ G1, const float* __restrict__ B1,
    const float* __restrict__ M1, const float* __restrict__ V1,
    unsigned short* __restrict__ qimg, unsigned short* __restrict__ kimg,
    float* __restrict__ v0pm, int L) {
  int pidx = blockIdx.x;
  int nPad = L - CW;
  int bI = pidx / nPad, l = CW + (pidx - bI * nPad);
  int tid = threadIdx.x;
  for (int o = tid; o < 1280; o += 256) {
    if (o < 1024) {
      float s = G0[o] * rsqrtf(V0[o] + 1e-5f);
      float sh = B0[o] - M0[o] * s;
      int nh = o >> 7, sp = (o >> 6) & 1, d = o & 63;
      unsigned short* dst = sp ? kimg : qimg;
      size_t rowoff = (((size_t)(bI * NHh + nh)) * L + l) * 128 + d;
      unsigned short hi = f2bf(sh);
      float hif = __uint_as_float((unsigned)hi << 16);
      dst[rowoff] = hi;
      dst[rowoff + 64] = f2bf(sh - hif);
    } else {
      int oc = o - 1024;
      float s = G1[oc] * rsqrtf(V1[oc] + 1e-5f);
      float sh = B1[oc] - M1[oc] * s;
      v0pm[((size_t)bI * L + l) * CC + oc] = sh;
    }
  }
}

// MFMA-gram fused attention level-pair. One wave per B*B-position block.
// pos = base0 + idx*s2, idx = a*B + b. Level A: digit a (stride B*s2), level B: digit b (stride s2).
// Gram G[J_idx][j_idx] = K[J_idx]·Q[j_idx] via mfma hi/lo 3-product; softmax slices from LDS.
template <int B, bool DO_A, bool DO_B>
__global__ __launch_bounds__(256) void attn_mfma(
    const unsigned short* __restrict__ qimg, const unsigned short* __restrict__ kimg,
    const float* __restrict__ vin, float* __restrict__ vout,
    int L, int s2, int bpb) {
  constexpr int B2 = B * B;
  constexpr int MT = (B2 + 15) / 16;
  __shared__ float S[4][256];
  int tid = threadIdx.x;
  int w = tid >> 6, lane = tid & 63;
  int gid = blockIdx.x * 4 + w;
  int bh = gid / bpb;
  int g = gid - bh * bpb;
  int hi_ = g / s2, lo_ = g - hi_ * s2;
  int base0 = hi_ * B2 * s2 + lo_;
  int cl = lane & 15, r4 = lane >> 4;
  int dd = lane & 31, half = lane >> 5;
  int bI = bh >> 3, nh = bh & 7;

  // fragment loads (A=K rows J, B=Q rows j; same lane pattern row=cl, k=r4*8)
  short8 kh[MT][2], kl[MT][2], qh[MT][2], ql[MT][2];
#pragma unroll
  for (int mt = 0; mt < MT; mt++) {
    int idx = mt * 16 + cl;
    if (idx > B2 - 1) idx = B2 - 1;  // clamped pad rows; results discarded
    size_t row = ((size_t)bh * L + base0 + idx * s2) * 128;
#pragma unroll
    for (int kt = 0; kt < 2; kt++) {
      int dof = kt * 32 + r4 * 8;
      kh[mt][kt] = *(const short8*)(kimg + row + dof);
      kl[mt][kt] = *(const short8*)(kimg + row + 64 + dof);
      qh[mt][kt] = *(const short8*)(qimg + row + dof);
      ql[mt][kt] = *(const short8*)(qimg + row + 64 + dof);
    }
  }
  size_t vBase = ((size_t)bI * L + base0) * CC + nh * HDd + dd;
  float vv[B2];
#pragma unroll
  for (int idx = 0; idx < B2; idx++) vv[idx] = vin[vBase + (size_t)(idx * s2) * CC];

  f32x4 C[MT][MT] = {};
#pragma unroll
  for (int kt = 0; kt < 2; kt++)
#pragma unroll
    for (int mt = 0; mt < MT; mt++)
#pragma unroll
      for (int nt = 0; nt < MT; nt++) {
        C[mt][nt] = __builtin_amdgcn_mfma_f32_16x16x32_bf16(kh[mt][kt], qh[nt][kt], C[mt][nt], 0, 0, 0);
        C[mt][nt] = __builtin_amdgcn_mfma_f32_16x16x32_bf16(kh[mt][kt], ql[nt][kt], C[mt][nt], 0, 0, 0);
        C[mt][nt] = __builtin_amdgcn_mfma_f32_16x16x32_bf16(kl[mt][kt], qh[nt][kt], C[mt][nt], 0, 0, 0);
      }
  // scatter needed (scaled) gram entries to per-wave LDS slabs
#pragma unroll
  for (int mt = 0; mt < MT; mt++)
#pragma unroll
    for (int nt = 0; nt < MT; nt++)
#pragma unroll
      for (int rr = 0; rr < 4; rr++) {
        int J_idx = mt * 16 + r4 * 4 + rr;
        int j_idx = nt * 16 + cl;
        if (J_idx < B2 && j_idx < B2) {
          float val = C[mt][nt][rr] * 0.125f;
          int Jq, bJ, jq, bj;
          if (B == 4) {
            Jq = J_idx >> 2; bJ = J_idx & 3; jq = j_idx >> 2; bj = j_idx & 3;
          } else {
            Jq = (J_idx * 205) >> 10; bJ = J_idx - Jq * 5;
            jq = (j_idx * 205) >> 10; bj = j_idx - jq * 5;
          }
          if (DO_A && bJ == bj) S[w][(bJ * B + Jq) * B + jq] = val;
          if (DO_B && Jq == jq) S[w][128 + (Jq * B + bJ) * B + bj] = val;
        }
      }
  // Level A: attention over digit a, groups fixed b (all lanes redundant)
  if (DO_A) {
#pragma unroll
    for (int b = 0; b < B; b++) {
      float tmp[B];
#pragma unroll
      for (int J = 0; J < B; J++) {
        float sc[B];
#pragma unroll
        for (int j = 0; j < B; j++) sc[j] = S[w][(b * B + J) * B + j];
        float mx = sc[0];
#pragma unroll
        for (int j = 1; j < B; j++) mx = fmaxf(mx, sc[j]);
        float sum = 0.f, acc = 0.f;
#pragma unroll
        for (int j = 0; j < B; j++) {
          float e = __expf(sc[j] - mx);
          sum += e;
          acc += e * vv[j * B + b];
        }
        tmp[J] = acc / sum;
      }
#pragma unroll
      for (int J = 0; J < B; J++) vv[J * B + b] = tmp[J];
    }
  }
  // Level B: attention over digit b, groups fixed a
  if (DO_B) {
#pragma unroll
    for (int a = 0; a < B; a++) {
      float tmp[B];
#pragma unroll
      for (int J = 0; J < B; J++) {
        float sc[B];
#pragma unroll
        for (int j = 0; j < B; j++) sc[j] = S[w][128 + (a * B + J) * B + j];
        float mx = sc[0];
#pragma unroll
        for (int j = 1; j < B; j++) mx = fmaxf(mx, sc[j]);
        float sum = 0.f, acc = 0.f;
#pragma unroll
        for (int j = 0; j < B; j++) {
          float e = __expf(sc[j] - mx);
          sum += e;
          acc += e * vv[a * B + j];
        }
        tmp[J] = acc / sum;
      }
#pragma unroll
      for (int J = 0; J < B; J++) vv[a * B + J] = tmp[J];
    }
  }
#pragma unroll
  for (int idx = 0; idx < B2; idx++)
    if ((idx & 1) == half) vout[vBase + (size_t)(idx * s2) * CC] = vv[idx];
}

// xcur(b,CW,256) += v2 + BN(dwconv3(v0pm))
__global__ __launch_bounds__(256) void combine(
    float* __restrict__ xcur, const float* __restrict__ v0pm,
    const float* __restrict__ vfin, const float* __restrict__ peW,
    const float* __restrict__ G, const float* __restrict__ Bb,
    const float* __restrict__ M, const float* __restrict__ V, int L) {
  int idx = blockIdx.x * 256 + threadIdx.x;
  if (idx >= CB * CC * CW) return;
  int ch = idx & 255;
  int t = idx >> 8;
  int l = t % CW;
  int bI = t / CW;
  size_t row = ((size_t)bI * L + l) * CC + ch;
  float left = (l > 0) ? v0pm[row - CC] : 0.f;
  float mid = v0pm[row];
  float right = (l + 1 < L) ? v0pm[row + CC] : 0.f;
  float conv = left * peW[ch * 3 + 0] + mid * peW[ch * 3 + 1] + right * peW[ch * 3 + 2];
  float s = G[ch] * rsqrtf(V[ch] + 1e-5f);
  float pe = conv * s + (Bb[ch] - M[ch] * s);
  xcur[((size_t)bI * CW + l) * CC + ch] += vfin[row] + pe;
}

extern "C" void kernel_launch(void* const* d_in, const int* in_sizes, int n_in,
                              void* d_out, int out_size, void* d_ws, size_t ws_size,
                              hipStream_t stream) {
  const float* x = (const float*)d_in[0];
  const float* qk_W = (const float*)d_in[1];
  const float* qk_g = (const float*)d_in[2];
  const float* qk_b = (const float*)d_in[3];
  const float* qk_m = (const float*)d_in[4];
  const float* qk_v = (const float*)d_in[5];
  const float* v_W = (const float*)d_in[6];
  const float* v_g = (const float*)d_in[7];
  const float* v_b = (const float*)d_in[8];
  const float* v_m = (const float*)d_in[9];
  const float* v_v = (const float*)d_in[10];
  const float* pe_W = (const float*)d_in[11];
  const float* pe_g = (const float*)d_in[12];
  const float* pe_b = (const float*)d_in[13];
  const float* pe_m = (const float*)d_in[14];
  const float* pe_v = (const float*)d_in[15];
  const float* proj_W = (const float*)d_in[16];
  const float* proj_g = (const float*)d_in[17];
  const float* proj_b = (const float*)d_in[18];
  const float* proj_m = (const float*)d_in[19];
  const float* proj_v = (const float*)d_in[20];

  char* ws = (char*)d_ws;
  size_t off = 0;
  auto alloc = [&](size_t bytes) {
    char* p = ws + off;
    off += (bytes + 255) & ~(size_t)255;
    return (void*)p;
  };
  const int Lmax = 4096;
  float* xcur = (float*)alloc((size_t)CB * CW * CC * 4);
  unsigned short* qimg = (unsigned short*)alloc((size_t)CB * NHh * Lmax * 128 * 2);
  unsigned short* kimg = (unsigned short*)alloc((size_t)CB * NHh * Lmax * 128 * 2);
  float* v0pm = (float*)alloc((size_t)CB * Lmax * CC * 4);
  float* vA = (float*)alloc((size_t)CB * Lmax * CC * 4);  // aliases Ximg during GEMM
  float* vB = (float*)alloc((size_t)CB * Lmax * CC * 4);
  unsigned short* Wimg = (unsigned short*)alloc((size_t)10 * 16 * 8192);
  unsigned short* Ximg = (unsigned short*)vA;
  (void)ws_size;

  {
    dim3 gt((CW + 63) / 64, 4, CB);
    transpose_x<<<gt, 256, 0, stream>>>(x, xcur);
  }

  const int P = CB * CW;
  const int ptiles = (P + 127) / 128;
  const int bases[2] = {5, 4};
  const int Ls[2] = {3125, 4096};
  int nElems = CB * CC * CW;
  for (int blk = 0; blk < 2; blk++) {
    int L = Ls[blk];
    prep_w<<<(1280 * 32 + 255) / 256, 256, 0, stream>>>(
        qk_W + (size_t)blk * 1024 * CC, 1024, v_W + (size_t)blk * CC * CC, Wimg, 1280);
    dim3 gx(ptiles, 4);
    prep_x<<<gx, 256, 0, stream>>>(xcur, Ximg, P);
    dim3 gg(ptiles, 10);
    gemm_bn<0><<<gg, 256, 0, stream>>>(
        Wimg, Ximg, qk_g + blk * 1024, qk_b + blk * 1024, qk_m + blk * 1024,
        qk_v + blk * 1024, v_g + blk * CC, v_b + blk * CC, v_m + blk * CC,
        v_v + blk * CC, qimg, kimg, v0pm, nullptr, L, P);
    if (L > CW) {
      pad_fill<<<CB * (L - CW), 256, 0, stream>>>(
          qk_g + blk * 1024, qk_b + blk * 1024, qk_m + blk * 1024, qk_v + blk * 1024,
          v_g + blk * CC, v_b + blk * CC, v_m + blk * CC, v_v + blk * CC,
          qimg, kimg, v0pm, L);
    }

    if (bases[blk] == 5) {
      int bpb = L / 25;  // 125
      int nb = CB * NHh * bpb / 4;
      attn_mfma<5, true, true><<<nb, 256, 0, stream>>>(qimg, kimg, v0pm, vA, L, 125, bpb);
      attn_mfma<5, true, true><<<nb, 256, 0, stream>>>(qimg, kimg, vA, vB, L, 5, bpb);
      attn_mfma<5, false, true><<<nb, 256, 0, stream>>>(qimg, kimg, vB, vA, L, 1, bpb);
    } else {
      int bpb = L / 16;  // 256
      int nb = CB * NHh * bpb / 4;
      attn_mfma<4, true, true><<<nb, 256, 0, stream>>>(qimg, kimg, v0pm, vA, L, 256, bpb);
      attn_mfma<4, true, true><<<nb, 256, 0, stream>>>(qimg, kimg, vA, vB, L, 16, bpb);
      attn_mfma<4, true, true><<<nb, 256, 0, stream>>>(qimg, kimg, vB, vA, L, 1, bpb);
    }
    combine<<<(nElems + 255) / 256, 256, 0, stream>>>(
        xcur, v0pm, vA, pe_W + (size_t)blk * CC * 3, pe_g + blk * CC,
        pe_b + blk * CC, pe_m + blk * CC, pe_v + blk * CC, L);
  }
  {
    prep_w<<<(256 * 32 + 255) / 256, 256, 0, stream>>>(proj_W, 256, nullptr, Wimg, 256);
    dim3 gx(ptiles, 4);
    prep_x<<<gx, 256, 0, stream>>>(xcur, Ximg, P);
    dim3 gg(ptiles, 2);
    gemm_bn<2><<<gg, 256, 0, stream>>>(
        Wimg, Ximg, proj_g, proj_b, proj_m, proj_v, nullptr, nullptr, nullptr,
        nullptr, nullptr, nullptr, nullptr, (float*)d_out, CW, P);
  }
}

// Round 6
// 362.050 us; speedup vs baseline: 1.6924x; 1.0312x over previous
//
#include <hip/hip_runtime.h>
#include <math.h>

constexpr int CW = 3125;   // valid width
constexpr int CC = 256;    // channels
constexpr int CB = 4;      // batch
constexpr int NHh = 8;     // heads
constexpr int KDd = 64;    // qk head dim
constexpr int HDd = 32;    // v head dim

typedef __attribute__((ext_vector_type(8))) short short8;
typedef __attribute__((ext_vector_type(4))) float f32x4;
typedef __attribute__((ext_vector_type(4))) unsigned int uint4v;

__device__ inline unsigned short f2bf(float x) {
  unsigned int u = __float_as_uint(x);
  unsigned int r = u + 0x7FFFu + ((u >> 16) & 1u);
  return (unsigned short)(r >> 16);
}

__device__ inline void gload_lds16(const void* g, void* l) {
  typedef __attribute__((address_space(3))) unsigned int lds_u32;
  typedef const __attribute__((address_space(1))) unsigned int glob_u32;
  __builtin_amdgcn_global_load_lds((glob_u32*)g, (lds_u32*)l, 16, 0, 0);
}

// x (b,256,CW) channel-major  ->  xcur (b,CW,256) position-major
__global__ __launch_bounds__(256) void transpose_x(const float* __restrict__ src,
                                                   float* __restrict__ dst) {
  __shared__ float sT[64][65];
  int l0 = blockIdx.x * 64, c0 = blockIdx.y * 64, bI = blockIdx.z;
  int tid = threadIdx.x;
  for (int i = tid; i < 4096; i += 256) {
    int ll = i & 63, cc = i >> 6;
    int l = l0 + ll;
    sT[cc][ll] = (l < CW) ? src[((size_t)bI * CC + c0 + cc) * CW + l] : 0.f;
  }
  __syncthreads();
  for (int i = tid; i < 4096; i += 256) {
    int cc = i & 63, ll = i >> 6;
    int l = l0 + ll;
    if (l < CW) dst[((size_t)bI * CW + l) * CC + c0 + cc] = sT[cc][ll];
  }
}

// Weight staging image: [otile][ktile=16][kchunk=4][o=128][16B]; ktiles 8-15 = lo copy
__global__ __launch_bounds__(256) void prep_w(const float* __restrict__ W0, int O0,
                                              const float* __restrict__ W1,
                                              unsigned short* __restrict__ img,
                                              int Ototal) {
  int t = blockIdx.x * 256 + threadIdx.x;
  if (t >= Ototal * 32) return;
  int o = t >> 5, ch = t & 31;
  const float* row = (o < O0) ? (W0 + (size_t)o * CC) : (W1 + (size_t)(o - O0) * CC);
  unsigned short h[8];
#pragma unroll
  for (int j = 0; j < 8; j++) h[j] = f2bf(row[ch * 8 + j]);
  uint4v v;
  v[0] = (unsigned)h[0] | ((unsigned)h[1] << 16);
  v[1] = (unsigned)h[2] | ((unsigned)h[3] << 16);
  v[2] = (unsigned)h[4] | ((unsigned)h[5] << 16);
  v[3] = (unsigned)h[6] | ((unsigned)h[7] << 16);
  int otile = o >> 7, oo = o & 127;
  int ktile = ch >> 2, kchunk = ch & 3;
  uint4v* img4 = (uint4v*)img;
  size_t idx = ((size_t)otile * 16 + ktile) * 512 + kchunk * 128 + oo;
  img4[idx] = v;
  img4[idx + 8 * 512] = v;
}

// x staging from xcur rows (dense p' = bI*CW+l), split hi/lo bf16.
__global__ __launch_bounds__(256) void prep_x(const float* __restrict__ X,
                                              unsigned short* __restrict__ img, int P) {
  int ptile = blockIdx.x, cq = blockIdx.y;
  int c0 = cq * 64;
  __shared__ float sX[64][129];
  int tid = threadIdx.x;
  for (int i = tid; i < 64 * 128; i += 256) {
    int cc = i & 63, pp = i >> 6;
    int p = ptile * 128 + pp;
    sX[cc][pp] = (p < P) ? X[(size_t)p * CC + c0 + cc] : 0.f;
  }
  __syncthreads();
  uint4v* img4 = (uint4v*)img;
  for (int i = tid; i < 1024; i += 256) {
    int ch = i >> 7, pp = i & 127;
    float f[8];
    unsigned short h[8], lo[8];
#pragma unroll
    for (int j = 0; j < 8; j++) f[j] = sX[ch * 8 + j][pp];
#pragma unroll
    for (int j = 0; j < 8; j++) {
      h[j] = f2bf(f[j]);
      float hif = __uint_as_float((unsigned)h[j] << 16);
      lo[j] = f2bf(f[j] - hif);
    }
    uint4v vh, vl;
    vh[0] = (unsigned)h[0] | ((unsigned)h[1] << 16);
    vh[1] = (unsigned)h[2] | ((unsigned)h[3] << 16);
    vh[2] = (unsigned)h[4] | ((unsigned)h[5] << 16);
    vh[3] = (unsigned)h[6] | ((unsigned)h[7] << 16);
    vl[0] = (unsigned)lo[0] | ((unsigned)lo[1] << 16);
    vl[1] = (unsigned)lo[2] | ((unsigned)lo[3] << 16);
    vl[2] = (unsigned)lo[4] | ((unsigned)lo[5] << 16);
    vl[3] = (unsigned)lo[6] | ((unsigned)lo[7] << 16);
    int ktile = cq * 2 + (ch >> 2), kchunk = ch & 3;
    size_t idx = ((size_t)ptile * 16 + ktile) * 512 + kchunk * 128 + pp;
    img4[idx] = vh;
    img4[idx + 8 * 512] = vl;
  }
}

// MFMA GEMM over dense valid positions p' = bI*CW + l. 2-phase double-buffered staging.
// XCD-group swizzle: all nOt otile-blocks of one ptile run consecutively on one XCD.
// MODE 0: fused qkv (O=1280) -> q/k bf16 hi/lo images [bh][L][64hi|64lo], v0pm (b,L,256) fp32
// MODE 2: proj (O=256) -> out (b,256,CW)
template <int MODE>
__global__ __launch_bounds__(256) void gemm_bn(
    const unsigned short* __restrict__ Aimg, const unsigned short* __restrict__ Ximg,
    const float* __restrict__ G0, const float* __restrict__ B0,
    const float* __restrict__ M0, const float* __restrict__ V0,
    const float* __restrict__ G1, const float* __restrict__ B1,
    const float* __restrict__ M1, const float* __restrict__ V1,
    unsigned short* __restrict__ qimg, unsigned short* __restrict__ kimg,
    float* __restrict__ v0pm, float* __restrict__ out, int L, int P,
    int nOt, int ptiles) {
  // swizzle decode: xcd = raw&7 owns ptiles {xcd, xcd+8, ...}; members = otiles
  int raw = blockIdx.x;
  int xcd = raw & 7;
  int t = raw >> 3;
  int ptile = (t / nOt) * 8 + xcd;
  int otile = t % nOt;
  if (ptile >= ptiles) return;
  __shared__ __align__(16) unsigned short sA[2][4096];
  __shared__ __align__(16) unsigned short sB[2][4096];
  int tid = threadIdx.x;
  int wid = tid >> 6, lane = tid & 63;
  int wr = wid >> 1, wc = wid & 1;
  f32x4 acc[4][4] = {};
  size_t aBase = ((size_t)otile * 16) * 4096;
  size_t bBase = ((size_t)ptile * 16) * 4096;
  int r = lane & 15, kb = lane >> 4;

  auto STAGE = [&](int buf, int kt) {
#pragma unroll
    for (int i = 0; i < 4; i++) {
      int c = wid * 4 + i;
      if (c < 8) {
        gload_lds16(Aimg + aBase + kt * 4096 + c * 512 + lane * 8,
                    &sA[buf][c * 512 + lane * 8]);
      } else {
        gload_lds16(Ximg + bBase + kt * 4096 + (c - 8) * 512 + lane * 8,
                    &sB[buf][(c - 8) * 512 + lane * 8]);
      }
    }
  };

  STAGE(0, 0);
  __syncthreads();
  for (int kt = 0; kt < 16; kt++) {
    int cur = kt & 1;
    if (kt < 15) STAGE(cur ^ 1, kt + 1);  // issue next-tile loads (overlap with MFMA)
    short8 a[4], b[4];
#pragma unroll
    for (int mi = 0; mi < 4; mi++)
      a[mi] = *(const short8*)&sA[cur][kb * 1024 + (wr * 64 + mi * 16 + r) * 8];
#pragma unroll
    for (int ni = 0; ni < 4; ni++)
      b[ni] = *(const short8*)&sB[cur][kb * 1024 + (wc * 64 + ni * 16 + r) * 8];
    if (MODE == 0) {
#pragma unroll
      for (int mi = 0; mi < 4; mi++)
#pragma unroll
        for (int ni = 0; ni < 4; ni++)
          acc[ni][mi] = __builtin_amdgcn_mfma_f32_16x16x32_bf16(b[ni], a[mi], acc[ni][mi], 0, 0, 0);
    } else {
#pragma unroll
      for (int mi = 0; mi < 4; mi++)
#pragma unroll
        for (int ni = 0; ni < 4; ni++)
          acc[mi][ni] = __builtin_amdgcn_mfma_f32_16x16x32_bf16(a[mi], b[ni], acc[mi][ni], 0, 0, 0);
    }
    __syncthreads();  // drains vmcnt (next stage ready) + lgkm; one barrier per kt
  }
  int cl = lane & 15, r4 = lane >> 4;
  if (MODE == 0) {
#pragma unroll
    for (int mi = 0; mi < 4; mi++) {
      int o = otile * 128 + wr * 64 + mi * 16 + cl;
      float s, sh;
      if (o >= 1024) {
        int oc = o - 1024;
        s = G1[oc] * rsqrtf(V1[oc] + 1e-5f);
        sh = B1[oc] - M1[oc] * s;
      } else {
        s = G0[o] * rsqrtf(V0[o] + 1e-5f);
        sh = B0[o] - M0[o] * s;
      }
      int nh = (o & 1023) >> 7, sp = (o >> 6) & 1, d = o & 63;
      int oc = o - 1024;
#pragma unroll
      for (int ni = 0; ni < 4; ni++) {
#pragma unroll
        for (int reg = 0; reg < 4; reg++) {
          int p = ptile * 128 + wc * 64 + ni * 16 + r4 * 4 + reg;
          if (p >= P) continue;
          int bI = p / CW, l = p - bI * CW;
          float y = acc[ni][mi][reg] * s + sh;
          if (o < 1024) {
            unsigned short* dst = sp ? kimg : qimg;
            size_t rowoff = (((size_t)(bI * NHh + nh)) * L + l) * 128 + d;
            unsigned short hi = f2bf(y);
            float hif = __uint_as_float((unsigned)hi << 16);
            dst[rowoff] = hi;
            dst[rowoff + 64] = f2bf(y - hif);
          } else {
            v0pm[((size_t)bI * L + l) * CC + oc] = y;
          }
        }
      }
    }
  } else {
#pragma unroll
    for (int mi = 0; mi < 4; mi++) {
#pragma unroll
      for (int reg = 0; reg < 4; reg++) {
        int o = otile * 128 + wr * 64 + mi * 16 + r4 * 4 + reg;
        float s = G0[o] * rsqrtf(V0[o] + 1e-5f);
        float sh = B0[o] - M0[o] * s;
#pragma unroll
        for (int ni = 0; ni < 4; ni++) {
          int p = ptile * 128 + wc * 64 + ni * 16 + cl;
          if (p >= P) continue;
          int bI = p / CW, l = p - bI * CW;
          out[((size_t)bI * CC + o) * CW + l] = acc[mi][ni][reg] * s + sh;
        }
      }
    }
  }
}

// Fill pad rows l in [CW, L): conv1x1(0)+BN = per-channel constant.
__global__ __launch_bounds__(256) void pad_fill(
    const float* __restrict__ G0, const float* __restrict__ B0,
    const float* __restrict__ M0, const float* __restrict__ V0,
    const float* __restrict__ G1, const float* __restrict__ B1,
    const float* __restrict__ M1, const float* __restrict__ V1,
    unsigned short* __restrict__ qimg, unsigned short* __restrict__ kimg,
    float* __restrict__ v0pm, int L) {
  int pidx = blockIdx.x;
  int nPad = L - CW;
  int bI = pidx / nPad, l = CW + (pidx - bI * nPad);
  int tid = threadIdx.x;
  for (int o = tid; o < 1280; o += 256) {
    if (o < 1024) {
      float s = G0[o] * rsqrtf(V0[o] + 1e-5f);
      float sh = B0[o] - M0[o] * s;
      int nh = o >> 7, sp = (o >> 6) & 1, d = o & 63;
      unsigned short* dst = sp ? kimg : qimg;
      size_t rowoff = (((size_t)(bI * NHh + nh)) * L + l) * 128 + d;
      unsigned short hi = f2bf(sh);
      float hif = __uint_as_float((unsigned)hi << 16);
      dst[rowoff] = hi;
      dst[rowoff + 64] = f2bf(sh - hif);
    } else {
      int oc = o - 1024;
      float s = G1[oc] * rsqrtf(V1[oc] + 1e-5f);
      float sh = B1[oc] - M1[oc] * s;
      v0pm[((size_t)bI * L + l) * CC + oc] = sh;
    }
  }
}

// MFMA-gram fused attention level-pair. One wave per B*B-position block.
template <int B, bool DO_A, bool DO_B>
__global__ __launch_bounds__(256) void attn_mfma(
    const unsigned short* __restrict__ qimg, const unsigned short* __restrict__ kimg,
    const float* __restrict__ vin, float* __restrict__ vout,
    int L, int s2, int bpb) {
  constexpr int B2 = B * B;
  constexpr int MT = (B2 + 15) / 16;
  __shared__ float S[4][256];
  int tid = threadIdx.x;
  int w = tid >> 6, lane = tid & 63;
  int gid = blockIdx.x * 4 + w;
  int bh = gid / bpb;
  int g = gid - bh * bpb;
  int hi_ = g / s2, lo_ = g - hi_ * s2;
  int base0 = hi_ * B2 * s2 + lo_;
  int cl = lane & 15, r4 = lane >> 4;
  int dd = lane & 31, half = lane >> 5;
  int bI = bh >> 3, nh = bh & 7;

  short8 kh[MT][2], kl[MT][2], qh[MT][2], ql[MT][2];
#pragma unroll
  for (int mt = 0; mt < MT; mt++) {
    int idx = mt * 16 + cl;
    if (idx > B2 - 1) idx = B2 - 1;
    size_t row = ((size_t)bh * L + base0 + idx * s2) * 128;
#pragma unroll
    for (int kt = 0; kt < 2; kt++) {
      int dof = kt * 32 + r4 * 8;
      kh[mt][kt] = *(const short8*)(kimg + row + dof);
      kl[mt][kt] = *(const short8*)(kimg + row + 64 + dof);
      qh[mt][kt] = *(const short8*)(qimg + row + dof);
      ql[mt][kt] = *(const short8*)(qimg + row + 64 + dof);
    }
  }
  size_t vBase = ((size_t)bI * L + base0) * CC + nh * HDd + dd;
  float vv[B2];
#pragma unroll
  for (int idx = 0; idx < B2; idx++) vv[idx] = vin[vBase + (size_t)(idx * s2) * CC];

  f32x4 C[MT][MT] = {};
#pragma unroll
  for (int kt = 0; kt < 2; kt++)
#pragma unroll
    for (int mt = 0; mt < MT; mt++)
#pragma unroll
      for (int nt = 0; nt < MT; nt++) {
        C[mt][nt] = __builtin_amdgcn_mfma_f32_16x16x32_bf16(kh[mt][kt], qh[nt][kt], C[mt][nt], 0, 0, 0);
        C[mt][nt] = __builtin_amdgcn_mfma_f32_16x16x32_bf16(kh[mt][kt], ql[nt][kt], C[mt][nt], 0, 0, 0);
        C[mt][nt] = __builtin_amdgcn_mfma_f32_16x16x32_bf16(kl[mt][kt], qh[nt][kt], C[mt][nt], 0, 0, 0);
      }
#pragma unroll
  for (int mt = 0; mt < MT; mt++)
#pragma unroll
    for (int nt = 0; nt < MT; nt++)
#pragma unroll
      for (int rr = 0; rr < 4; rr++) {
        int J_idx = mt * 16 + r4 * 4 + rr;
        int j_idx = nt * 16 + cl;
        if (J_idx < B2 && j_idx < B2) {
          float val = C[mt][nt][rr] * 0.125f;
          int Jq, bJ, jq, bj;
          if (B == 4) {
            Jq = J_idx >> 2; bJ = J_idx & 3; jq = j_idx >> 2; bj = j_idx & 3;
          } else {
            Jq = (J_idx * 205) >> 10; bJ = J_idx - Jq * 5;
            jq = (j_idx * 205) >> 10; bj = j_idx - jq * 5;
          }
          if (DO_A && bJ == bj) S[w][(bJ * B + Jq) * B + jq] = val;
          if (DO_B && Jq == jq) S[w][128 + (Jq * B + bJ) * B + bj] = val;
        }
      }
  if (DO_A) {
#pragma unroll
    for (int b = 0; b < B; b++) {
      float tmp[B];
#pragma unroll
      for (int J = 0; J < B; J++) {
        float sc[B];
#pragma unroll
        for (int j = 0; j < B; j++) sc[j] = S[w][(b * B + J) * B + j];
        float mx = sc[0];
#pragma unroll
        for (int j = 1; j < B; j++) mx = fmaxf(mx, sc[j]);
        float sum = 0.f, acc = 0.f;
#pragma unroll
        for (int j = 0; j < B; j++) {
          float e = __expf(sc[j] - mx);
          sum += e;
          acc += e * vv[j * B + b];
        }
        tmp[J] = acc / sum;
      }
#pragma unroll
      for (int J = 0; J < B; J++) vv[J * B + b] = tmp[J];
    }
  }
  if (DO_B) {
#pragma unroll
    for (int a = 0; a < B; a++) {
      float tmp[B];
#pragma unroll
      for (int J = 0; J < B; J++) {
        float sc[B];
#pragma unroll
        for (int j = 0; j < B; j++) sc[j] = S[w][128 + (a * B + J) * B + j];
        float mx = sc[0];
#pragma unroll
        for (int j = 1; j < B; j++) mx = fmaxf(mx, sc[j]);
        float sum = 0.f, acc = 0.f;
#pragma unroll
        for (int j = 0; j < B; j++) {
          float e = __expf(sc[j] - mx);
          sum += e;
          acc += e * vv[a * B + j];
        }
        tmp[J] = acc / sum;
      }
#pragma unroll
      for (int J = 0; J < B; J++) vv[a * B + J] = tmp[J];
    }
  }
#pragma unroll
  for (int idx = 0; idx < B2; idx++)
    if ((idx & 1) == half) vout[vBase + (size_t)(idx * s2) * CC] = vv[idx];
}

// xcur(b,CW,256) += v2 + BN(dwconv3(v0pm))
__global__ __launch_bounds__(256) void combine(
    float* __restrict__ xcur, const float* __restrict__ v0pm,
    const float* __restrict__ vfin, const float* __restrict__ peW,
    const float* __restrict__ G, const float* __restrict__ Bb,
    const float* __restrict__ M, const float* __restrict__ V, int L) {
  int idx = blockIdx.x * 256 + threadIdx.x;
  if (idx >= CB * CC * CW) return;
  int ch = idx & 255;
  int t = idx >> 8;
  int l = t % CW;
  int bI = t / CW;
  size_t row = ((size_t)bI * L + l) * CC + ch;
  float left = (l > 0) ? v0pm[row - CC] : 0.f;
  float mid = v0pm[row];
  float right = (l + 1 < L) ? v0pm[row + CC] : 0.f;
  float conv = left * peW[ch * 3 + 0] + mid * peW[ch * 3 + 1] + right * peW[ch * 3 + 2];
  float s = G[ch] * rsqrtf(V[ch] + 1e-5f);
  float pe = conv * s + (Bb[ch] - M[ch] * s);
  xcur[((size_t)bI * CW + l) * CC + ch] += vfin[row] + pe;
}

extern "C" void kernel_launch(void* const* d_in, const int* in_sizes, int n_in,
                              void* d_out, int out_size, void* d_ws, size_t ws_size,
                              hipStream_t stream) {
  const float* x = (const float*)d_in[0];
  const float* qk_W = (const float*)d_in[1];
  const float* qk_g = (const float*)d_in[2];
  const float* qk_b = (const float*)d_in[3];
  const float* qk_m = (const float*)d_in[4];
  const float* qk_v = (const float*)d_in[5];
  const float* v_W = (const float*)d_in[6];
  const float* v_g = (const float*)d_in[7];
  const float* v_b = (const float*)d_in[8];
  const float* v_m = (const float*)d_in[9];
  const float* v_v = (const float*)d_in[10];
  const float* pe_W = (const float*)d_in[11];
  const float* pe_g = (const float*)d_in[12];
  const float* pe_b = (const float*)d_in[13];
  const float* pe_m = (const float*)d_in[14];
  const float* pe_v = (const float*)d_in[15];
  const float* proj_W = (const float*)d_in[16];
  const float* proj_g = (const float*)d_in[17];
  const float* proj_b = (const float*)d_in[18];
  const float* proj_m = (const float*)d_in[19];
  const float* proj_v = (const float*)d_in[20];

  char* ws = (char*)d_ws;
  size_t off = 0;
  auto alloc = [&](size_t bytes) {
    char* p = ws + off;
    off += (bytes + 255) & ~(size_t)255;
    return (void*)p;
  };
  const int Lmax = 4096;
  float* xcur = (float*)alloc((size_t)CB * CW * CC * 4);
  unsigned short* qimg = (unsigned short*)alloc((size_t)CB * NHh * Lmax * 128 * 2);
  unsigned short* kimg = (unsigned short*)alloc((size_t)CB * NHh * Lmax * 128 * 2);
  float* v0pm = (float*)alloc((size_t)CB * Lmax * CC * 4);
  float* vA = (float*)alloc((size_t)CB * Lmax * CC * 4);  // aliases Ximg during GEMM
  float* vB = (float*)alloc((size_t)CB * Lmax * CC * 4);
  unsigned short* Wimg = (unsigned short*)alloc((size_t)10 * 16 * 8192);
  unsigned short* Ximg = (unsigned short*)vA;
  (void)ws_size;

  {
    dim3 gt((CW + 63) / 64, 4, CB);
    transpose_x<<<gt, 256, 0, stream>>>(x, xcur);
  }

  const int P = CB * CW;
  const int ptiles = (P + 127) / 128;      // 98
  const int pgroups8 = (ptiles + 7) / 8;   // 13
  const int bases[2] = {5, 4};
  const int Ls[2] = {3125, 4096};
  int nElems = CB * CC * CW;
  for (int blk = 0; blk < 2; blk++) {
    int L = Ls[blk];
    prep_w<<<(1280 * 32 + 255) / 256, 256, 0, stream>>>(
        qk_W + (size_t)blk * 1024 * CC, 1024, v_W + (size_t)blk * CC * CC, Wimg, 1280);
    dim3 gx(ptiles, 4);
    prep_x<<<gx, 256, 0, stream>>>(xcur, Ximg, P);
    gemm_bn<0><<<8 * pgroups8 * 10, 256, 0, stream>>>(
        Wimg, Ximg, qk_g + blk * 1024, qk_b + blk * 1024, qk_m + blk * 1024,
        qk_v + blk * 1024, v_g + blk * CC, v_b + blk * CC, v_m + blk * CC,
        v_v + blk * CC, qimg, kimg, v0pm, nullptr, L, P, 10, ptiles);
    if (L > CW) {
      pad_fill<<<CB * (L - CW), 256, 0, stream>>>(
          qk_g + blk * 1024, qk_b + blk * 1024, qk_m + blk * 1024, qk_v + blk * 1024,
          v_g + blk * CC, v_b + blk * CC, v_m + blk * CC, v_v + blk * CC,
          qimg, kimg, v0pm, L);
    }

    if (bases[blk] == 5) {
      int bpb = L / 25;  // 125
      int nb = CB * NHh * bpb / 4;
      attn_mfma<5, true, true><<<nb, 256, 0, stream>>>(qimg, kimg, v0pm, vA, L, 125, bpb);
      attn_mfma<5, true, true><<<nb, 256, 0, stream>>>(qimg, kimg, vA, vB, L, 5, bpb);
      attn_mfma<5, false, true><<<nb, 256, 0, stream>>>(qimg, kimg, vB, vA, L, 1, bpb);
    } else {
      int bpb = L / 16;  // 256
      int nb = CB * NHh * bpb / 4;
      attn_mfma<4, true, true><<<nb, 256, 0, stream>>>(qimg, kimg, v0pm, vA, L, 256, bpb);
      attn_mfma<4, true, true><<<nb, 256, 0, stream>>>(qimg, kimg, vA, vB, L, 16, bpb);
      attn_mfma<4, true, true><<<nb, 256, 0, stream>>>(qimg, kimg, vB, vA, L, 1, bpb);
    }
    combine<<<(nElems + 255) / 256, 256, 0, stream>>>(
        xcur, v0pm, vA, pe_W + (size_t)blk * CC * 3, pe_g + blk * CC,
        pe_b + blk * CC, pe_m + blk * CC, pe_v + blk * CC, L);
  }
  {
    prep_w<<<(256 * 32 + 255) / 256, 256, 0, stream>>>(proj_W, 256, nullptr, Wimg, 256);
    dim3 gx(ptiles, 4);
    prep_x<<<gx, 256, 0, stream>>>(xcur, Ximg, P);
    gemm_bn<2><<<8 * pgroups8 * 2, 256, 0, stream>>>(
        Wimg, Ximg, proj_g, proj_b, proj_m, proj_v, nullptr, nullptr, nullptr,
        nullptr, nullptr, nullptr, nullptr, (float*)d_out, CW, P, 2, ptiles);
  }
}